// Round 6
// baseline (249.573 us; speedup 1.0000x reference)
//
#include <hip/hip_runtime.h>

// Problem shape (fixed by setup_inputs): B=2, C=4, D=128, H=192, W=192
#define NB 2
#define NS (128 * 192 * 192)      // spatial voxels per batch = 4718592
#define NTOT (NB * NS)            // 9437184
#define NSQ (NS / 4)              // float4-quads per batch = 1179648
#define EPSF 1e-8f
#define INF_BITS 0x7F800000u

// R13 geometry (resubmit after broker timeout): 2048 blocks = 8 blocks/CU =
// 32 waves/CU (hardware max at VGPR<=64). Single-variable change vs R9/R12
// (proven best, 24 waves/CU): more outstanding reads per CU. NSQ/STRIDE =
// 4.5, so per batch blocks bid<512 run 5 sweeps, bid>=512 run 4
// (block-uniform predicate, NSQ%256==0; every CU gets exactly 4x5 + 4x4
// block-sweeps -> balanced).
#define TPB 256
#define BPB 1024                   // blocks per batch
#define BLOCKS (2 * BPB)           // 2048
#define STRIDE (BPB * TPB)         // 262144 quads per sweep
#define MAXIT 5                    // 4 full sweeps + 1 partial (bid<512)

// Decomposition: loss = -(R0 + sum_{b,j} s_bj*(P_bj - mn_bj*Q_bj)) / NTOT
//   P_bj = sum z_j*(a_j-lse), Q_bj = sum (a_j-lse), R0 = sum (t==0)*(a_0-lse)
// part layout: 16 floats per block: [0..2]=mn [3..5]=mx [6..8]=P [9..11]=Q [12]=R0

typedef float __attribute__((ext_vector_type(4))) f32x4;
typedef int   __attribute__((ext_vector_type(4))) i32x4;

__device__ __forceinline__ f32x4 ldnt_f4(const float* p) {
    return __builtin_nontemporal_load((const f32x4*)p);
}
__device__ __forceinline__ i32x4 ldnt_i4(const int* p) {
    return __builtin_nontemporal_load((const i32x4*)p);
}

// R13: theory = per-CU outstanding-read capacity limits the 3.16 TB/s read
// rate (ILP depth/VGPR changes were null in R10/R11; writes hit 6.86 TB/s).
// TLP is the one untested axis that scales outstanding reads per CU:
// 24 -> 32 waves/CU. waves_per_eu(4,8) keeps the allocator at <=64 VGPR
// (R9's natural count) so 8 waves/SIMD are resident.
__global__ __launch_bounds__(TPB)
__attribute__((amdgpu_waves_per_eu(4, 8)))
void k_fused(const float* __restrict__ x,
             const int* __restrict__ tgt,
             const float* __restrict__ dist,
             float* __restrict__ part) {
    const int b = (blockIdx.x >= BPB) ? 1 : 0;
    const int bid = blockIdx.x - b * BPB;
    const int q0 = bid * TPB + threadIdx.x;
    // 4 full sweeps cover 4*STRIDE = 1048576 quads; remaining 131072 quads
    // (= 512 blocks x 256) go to bid < 512.  Block-uniform.
    const int niters = (bid < (NSQ - 4 * STRIDE) / TPB) ? MAXIT : (MAXIT - 1);

    const float* xb = x + (size_t)b * 4 * NSQ * 4;   // batch base (floats)
    const int*   tb = tgt + (size_t)b * NSQ * 4;
    const float* db = dist + (size_t)b * NSQ * 4;

    float mn1 = __uint_as_float(INF_BITS), mn2 = mn1, mn3 = mn1;
    float mx1 = 0.f, mx2 = 0.f, mx3 = 0.f;
    float P1 = 0.f, P2 = 0.f, P3 = 0.f;
    float Q1 = 0.f, Q2 = 0.f, Q3 = 0.f;
    float R0 = 0.f;

    auto vox = [&](float a0, float a1, float a2, float a3, int tt, float dv) {
        float m = fmaxf(fmaxf(a0, a1), fmaxf(a2, a3));
        float e = __expf(a0 - m) + __expf(a1 - m) + __expf(a2 - m) + __expf(a3 - m);
        float lse = m + __logf(e);
        float z1 = (tt == 1) ? dv : 0.f;
        float z2 = (tt == 2) ? dv : 0.f;
        float z3 = (tt == 3) ? dv : 0.f;
        mn1 = fminf(mn1, z1); mx1 = fmaxf(mx1, z1);
        mn2 = fminf(mn2, z2); mx2 = fmaxf(mx2, z2);
        mn3 = fminf(mn3, z3); mx3 = fmaxf(mx3, z3);
        float l1 = a1 - lse, l2 = a2 - lse, l3 = a3 - lse;
        P1 += z1 * l1; P2 += z2 * l2; P3 += z3 * l3;
        Q1 += l1; Q2 += l2; Q3 += l3;
        R0 += (tt == 0) ? (a0 - lse) : 0.f;
    };

    // Rotating-register pipeline with non-temporal streamed loads (R9).
    f32x4 cx0 = ldnt_f4(xb + (size_t)q0 * 4);
    f32x4 cx1 = ldnt_f4(xb + (size_t)(q0 + NSQ) * 4);
    f32x4 cx2 = ldnt_f4(xb + (size_t)(q0 + 2 * NSQ) * 4);
    f32x4 cx3 = ldnt_f4(xb + (size_t)(q0 + 3 * NSQ) * 4);
    i32x4 ct  = ldnt_i4(tb + (size_t)q0 * 4);
    f32x4 cd  = ldnt_f4(db + (size_t)q0 * 4);

#pragma unroll 1
    for (int i = 0; i < niters; i++) {
        f32x4 nx0, nx1, nx2, nx3, nd;
        i32x4 nt;
        if (i + 1 < niters) {
            const int qn = q0 + (i + 1) * STRIDE;
            nx0 = ldnt_f4(xb + (size_t)qn * 4);
            nx1 = ldnt_f4(xb + (size_t)(qn + NSQ) * 4);
            nx2 = ldnt_f4(xb + (size_t)(qn + 2 * NSQ) * 4);
            nx3 = ldnt_f4(xb + (size_t)(qn + 3 * NSQ) * 4);
            nt  = ldnt_i4(tb + (size_t)qn * 4);
            nd  = ldnt_f4(db + (size_t)qn * 4);
        }
        vox(cx0.x, cx1.x, cx2.x, cx3.x, ct.x, cd.x);
        vox(cx0.y, cx1.y, cx2.y, cx3.y, ct.y, cd.y);
        vox(cx0.z, cx1.z, cx2.z, cx3.z, ct.z, cd.z);
        vox(cx0.w, cx1.w, cx2.w, cx3.w, ct.w, cd.w);
        if (i + 1 < niters) {
            cx0 = nx0; cx1 = nx1; cx2 = nx2; cx3 = nx3; ct = nt; cd = nd;
        }
    }

    // wave(64) butterfly over the 13 accumulators
    for (int off = 32; off; off >>= 1) {
        mn1 = fminf(mn1, __shfl_down(mn1, off, 64));
        mn2 = fminf(mn2, __shfl_down(mn2, off, 64));
        mn3 = fminf(mn3, __shfl_down(mn3, off, 64));
        mx1 = fmaxf(mx1, __shfl_down(mx1, off, 64));
        mx2 = fmaxf(mx2, __shfl_down(mx2, off, 64));
        mx3 = fmaxf(mx3, __shfl_down(mx3, off, 64));
        P1 += __shfl_down(P1, off, 64);
        P2 += __shfl_down(P2, off, 64);
        P3 += __shfl_down(P3, off, 64);
        Q1 += __shfl_down(Q1, off, 64);
        Q2 += __shfl_down(Q2, off, 64);
        Q3 += __shfl_down(Q3, off, 64);
        R0 += __shfl_down(R0, off, 64);
    }

    __shared__ float sv[4][13];
    const int wid = threadIdx.x >> 6;
    if ((threadIdx.x & 63) == 0) {
        sv[wid][0] = mn1; sv[wid][1] = mn2; sv[wid][2] = mn3;
        sv[wid][3] = mx1; sv[wid][4] = mx2; sv[wid][5] = mx3;
        sv[wid][6] = P1;  sv[wid][7] = P2;  sv[wid][8] = P3;
        sv[wid][9] = Q1;  sv[wid][10] = Q2; sv[wid][11] = Q3;
        sv[wid][12] = R0;
    }
    __syncthreads();
    const int i = threadIdx.x;
    if (i < 13) {
        float v = sv[0][i];
        if (i < 3)      v = fminf(fminf(v, sv[1][i]), fminf(sv[2][i], sv[3][i]));
        else if (i < 6) v = fmaxf(fmaxf(v, sv[1][i]), fmaxf(sv[2][i], sv[3][i]));
        else            v = v + sv[1][i] + sv[2][i] + sv[3][i];
        part[(size_t)blockIdx.x * 16 + i] = v;   // plain store — NO atomics
    }
}

// 512 threads, 1 block: thread t reduces 4 rows of one batch (BPB=1024).
// t<256 -> batch 0 rows {lane, lane+256, lane+512, lane+768}; t>=256 -> batch 1.
// Waves 0..3 are pure batch-0, waves 4..7 pure batch-1.
__global__ __launch_bounds__(512, 1)
void k_final(const float* __restrict__ part, float* __restrict__ out) {
    const int t = threadIdx.x;
    const int batch = t >> 8;
    const int lane8 = t & 255;

    float mn[3] = {__uint_as_float(INF_BITS), __uint_as_float(INF_BITS), __uint_as_float(INF_BITS)};
    float mx[3] = {0.f, 0.f, 0.f};
    double P[3] = {0, 0, 0}, Q[3] = {0, 0, 0}, R0 = 0;

#pragma unroll
    for (int k = 0; k < 4; k++) {
        const float4* r = (const float4*)(part + (size_t)(batch * BPB + k * 256 + lane8) * 16);
        float4 r0 = r[0];  // mn1 mn2 mn3 mx1
        float4 r1 = r[1];  // mx2 mx3 P1  P2
        float4 r2 = r[2];  // P3  Q1  Q2  Q3
        float4 r3 = r[3];  // R0  -   -   -
        mn[0] = fminf(mn[0], r0.x); mn[1] = fminf(mn[1], r0.y); mn[2] = fminf(mn[2], r0.z);
        mx[0] = fmaxf(mx[0], r0.w); mx[1] = fmaxf(mx[1], r1.x); mx[2] = fmaxf(mx[2], r1.y);
        P[0] += (double)r1.z; P[1] += (double)r1.w; P[2] += (double)r2.x;
        Q[0] += (double)r2.y; Q[1] += (double)r2.z; Q[2] += (double)r2.w;
        R0 += (double)r3.x;
    }

    for (int off = 32; off; off >>= 1) {
#pragma unroll
        for (int j = 0; j < 3; j++) {
            mn[j] = fminf(mn[j], __shfl_down(mn[j], off, 64));
            mx[j] = fmaxf(mx[j], __shfl_down(mx[j], off, 64));
            P[j] += __shfl_down(P[j], off, 64);
            Q[j] += __shfl_down(Q[j], off, 64);
        }
        R0 += __shfl_down(R0, off, 64);
    }

    __shared__ float smn[8][3], smx[8][3];
    __shared__ double sP[8][3], sQ[8][3], sR[8];
    const int wid = t >> 6;   // waves 0..3 = batch 0, waves 4..7 = batch 1
    if ((t & 63) == 0) {
#pragma unroll
        for (int j = 0; j < 3; j++) {
            smn[wid][j] = mn[j]; smx[wid][j] = mx[j];
            sP[wid][j] = P[j];   sQ[wid][j] = Q[j];
        }
        sR[wid] = R0;
    }
    __syncthreads();
    if (t == 0) {
        double acc = 0.0;
#pragma unroll
        for (int b = 0; b < 2; b++) {
            double Pb[3] = {0, 0, 0}, Qb[3] = {0, 0, 0};
            float mnb[3], mxb[3];
#pragma unroll
            for (int j = 0; j < 3; j++) { mnb[j] = __uint_as_float(INF_BITS); mxb[j] = 0.f; }
#pragma unroll
            for (int w = 4 * b; w < 4 * b + 4; w++) {
                acc += sR[w];
#pragma unroll
                for (int j = 0; j < 3; j++) {
                    mnb[j] = fminf(mnb[j], smn[w][j]);
                    mxb[j] = fmaxf(mxb[j], smx[w][j]);
                    Pb[j] += sP[w][j];
                    Qb[j] += sQ[w][j];
                }
            }
#pragma unroll
            for (int j = 0; j < 3; j++) {
                float sf = 1.0f / (mxb[j] + EPSF - mnb[j]);   // mirror reference fp32 scale
                acc += (double)sf * (Pb[j] - (double)mnb[j] * Qb[j]);
            }
        }
        out[0] = (float)(-acc / (double)NTOT);
    }
}

extern "C" void kernel_launch(void* const* d_in, const int* in_sizes, int n_in,
                              void* d_out, int out_size, void* d_ws, size_t ws_size,
                              hipStream_t stream) {
    const float* net = (const float*)d_in[0];   // [B, C, D, H, W] fp32
    const int* tgt = (const int*)d_in[1];       // [B, 1, D, H, W] int
    const float* dist = (const float*)d_in[2];  // [B, D, H, W] fp32
    float* part = (float*)d_ws;                 // 2048 x 16 floats = 128 KB

    k_fused<<<BLOCKS, TPB, 0, stream>>>(net, tgt, dist, part);
    k_final<<<1, 512, 0, stream>>>(part, (float*)d_out);
}